// Round 4
// baseline (205.491 us; speedup 1.0000x reference)
//
#include <hip/hip_runtime.h>

#define NTOK  16384   // B*T
#define KDIM  512
#define NQKV  1536
#define TT    4096

using frag8   = __attribute__((ext_vector_type(8))) short;
using floatx4 = __attribute__((ext_vector_type(4))) float;

__device__ __forceinline__ unsigned short f2b(float f) {
  union { float f; unsigned u; } v; v.f = f;
  unsigned r = v.u + 0x7fffu + ((v.u >> 16) & 1u);
  return (unsigned short)(r >> 16);
}
__device__ __forceinline__ float b2f(unsigned short s) {
  union { unsigned u; float f; } v; v.u = ((unsigned)s) << 16; return v.f;
}

__device__ __forceinline__ void gl_lds16(const void* g, void* l) {
  __builtin_amdgcn_global_load_lds((__attribute__((address_space(1))) const void*)g,
                                   (__attribute__((address_space(3))) void*)l,
                                   16, 0, 0);
}

// ---------------- convert kernels ----------------
__global__ __launch_bounds__(256) void cvt_x(const float* __restrict__ x,
                                             unsigned short* __restrict__ xb) {
  const size_t i = (size_t)blockIdx.x * 256 + threadIdx.x;
  const float4 v = ((const float4*)x)[i];
  ushort4 o;
  o.x = f2b(v.x); o.y = f2b(v.y); o.z = f2b(v.z); o.w = f2b(v.w);
  ((ushort4*)xb)[i] = o;
}

__global__ __launch_bounds__(256) void prep_weights(
    const float* __restrict__ Wq, const float* __restrict__ Wk,
    const float* __restrict__ Wv, const float* __restrict__ Wp,
    const float* __restrict__ bq, const float* __restrict__ bk,
    const float* __restrict__ bv,
    unsigned short* __restrict__ wqkv, unsigned short* __restrict__ wp,
    float* __restrict__ bias_qkv) {
  const int idx = blockIdx.x * 256 + threadIdx.x;
  if (idx < 786432) {                       // 1536*512
    const int m = idx >> 9, i = idx & 511;
    const float* W = (m < 512) ? Wq : ((m < 1024) ? Wk : Wv);
    wqkv[idx] = f2b(W[(m & 511) * 512 + i]);
    return;
  }
  const int j = idx - 786432;
  if (j < 262144) { wp[j] = f2b(Wp[j]); return; }
  const int c = j - 262144;
  if (c < 1536)
    bias_qkv[c] = (c < 512) ? bq[c] : ((c < 1024) ? bk[c - 512] : bv[c - 1024]);
}

// ---------------- QKV GEMM: 256x128 tile, fused softmax, bf16 store ----------------
__global__ __launch_bounds__(256, 2) void gemm_qkv(
    const unsigned short* __restrict__ A,
    const unsigned short* __restrict__ Bm,
    const float* __restrict__ bias,
    unsigned short* __restrict__ C)
{
  __shared__ unsigned short sh[128 * 128];   // 32 KB: As 256x32 | Bs 128x32; reused as os 128x128
  unsigned short* As = sh;
  unsigned short* Bs = sh + 256 * 32;
  const int tid  = threadIdx.x;
  const int wave = tid >> 6;
  const int lane = tid & 63;
  const int quad = lane >> 4;
  const int lr   = lane & 15;
  const int bid  = ((blockIdx.x & 7) * 96) + (blockIdx.x >> 3);   // grid 768
  const int bn   = (bid % 12) << 7;
  const int bm   = (bid / 12) << 8;
  const int wm   = wave << 6;

  floatx4 acc[4][8] = {};

  const int srow = tid >> 2;
  const int scol = (tid & 3) << 3;
  const unsigned short* Ag = A + (size_t)(bm + srow) * 512 + scol;
  const unsigned short* Bg = Bm + (size_t)(bn + srow) * 512 + scol;
  unsigned short* Al = As + (wave << 9);
  unsigned short* Bl = Bs + (wave << 9);

  for (int k0 = 0; k0 < 512; k0 += 32) {
    __syncthreads();
    gl_lds16(Ag + k0, Al);
    gl_lds16(Ag + 64 * 512 + k0, Al + 64 * 32);
    gl_lds16(Ag + 128 * 512 + k0, Al + 128 * 32);
    gl_lds16(Ag + 192 * 512 + k0, Al + 192 * 32);
    gl_lds16(Bg + k0, Bl);
    gl_lds16(Bg + 64 * 512 + k0, Bl + 64 * 32);
    __syncthreads();

    frag8 af[4], bf[8];
#pragma unroll
    for (int i = 0; i < 4; i++)
      af[i] = *(const frag8*)&As[(wm + (i << 4) + lr) * 32 + (quad << 3)];
#pragma unroll
    for (int j = 0; j < 8; j++)
      bf[j] = *(const frag8*)&Bs[((j << 4) + lr) * 32 + (quad << 3)];
#pragma unroll
    for (int i = 0; i < 4; i++)
#pragma unroll
      for (int j = 0; j < 8; j++)
        acc[i][j] = __builtin_amdgcn_mfma_f32_16x16x32_bf16(af[i], bf[j], acc[i][j], 0, 0, 0);
  }

  const int ccol0 = bn + lr;
#pragma unroll
  for (int j = 0; j < 8; j++) {
    const float bv = bias[ccol0 + (j << 4)];
#pragma unroll
    for (int i = 0; i < 4; i++)
#pragma unroll
      for (int r = 0; r < 4; r++)
        acc[i][j][r] += bv;
  }

  const int region = bn >> 9;   // 0=q, 1=k, 2=v (block-uniform)
  if (region < 2) {
#pragma unroll
    for (int i = 0; i < 4; i++)
#pragma unroll
      for (int r = 0; r < 4; r++) {
        float e0 = __expf(acc[i][0][r]);
        float e1 = __expf(acc[i][1][r]);
        float e2 = __expf(acc[i][2][r]);
        float e3 = __expf(acc[i][3][r]);
        float e4 = __expf(acc[i][4][r]);
        float e5 = __expf(acc[i][5][r]);
        float e6 = __expf(acc[i][6][r]);
        float e7 = __expf(acc[i][7][r]);
        float sl = e0 + e1 + e2 + e3;
        float sg = e4 + e5 + e6 + e7;
        sl += __shfl_xor(sl, 1); sl += __shfl_xor(sl, 2);
        sl += __shfl_xor(sl, 4); sl += __shfl_xor(sl, 8);
        sg += __shfl_xor(sg, 1); sg += __shfl_xor(sg, 2);
        sg += __shfl_xor(sg, 4); sg += __shfl_xor(sg, 8);
        const float il = 1.f / sl, ig = 1.f / sg;
        acc[i][0][r] = e0 * il; acc[i][1][r] = e1 * il;
        acc[i][2][r] = e2 * il; acc[i][3][r] = e3 * il;
        acc[i][4][r] = e4 * ig; acc[i][5][r] = e5 * ig;
        acc[i][6][r] = e6 * ig; acc[i][7][r] = e7 * ig;
      }
  }

  // coalesced bf16 store: 2 passes, 2 waves repack concurrently into os[128][128]
  unsigned short* os = sh;
#pragma unroll
  for (int p = 0; p < 2; p++) {
    __syncthreads();
    if ((wave >> 1) == p) {
      const int rb = (wave & 1) << 6;
#pragma unroll
      for (int i = 0; i < 4; i++)
#pragma unroll
        for (int j = 0; j < 8; j++)
#pragma unroll
          for (int r = 0; r < 4; r++)
            os[(rb + (i << 4) + (quad << 2) + r) * 128 + (j << 4) + lr] = f2b(acc[i][j][r]);
    }
    __syncthreads();
#pragma unroll
    for (int it = 0; it < 8; it++) {
      const int idx = (it << 8) + tid;   // 2048 uint4
      const int row = idx >> 4;
      const int c8  = (idx & 15) << 3;
      *(uint4*)(C + (size_t)(bm + (p << 7) + row) * NQKV + bn + c8) =
          *(const uint4*)&os[row * 128 + c8];
    }
  }
}

// ---------------- partial ctxT[e][d] + ksum partial per (chunk,bh) ----------------
__global__ __launch_bounds__(256) void kv_context(const unsigned short* __restrict__ qkv,
                                                  float* __restrict__ part,
                                                  float* __restrict__ ksp) {
  const int bid = blockIdx.x;          // bh(32) x tc(32), tc-fast
  const int tc  = bid & 31;
  const int bh  = bid >> 5;
  const int b   = bh >> 3, h = bh & 7;
  __shared__ unsigned short kb16[16 * 64];
  __shared__ unsigned short vb16[16 * 64];
  __shared__ float ksred[16 * 64];
  const int tid = threadIdx.x;
  const int wave = tid >> 6;
  const int lane = tid & 63;
  const int ty = tid >> 4, tx = tid & 15;
  floatx4 acc[4] = {};
  floatx4 ksacc = {0.f, 0.f, 0.f, 0.f};

  const int t0 = b * TT + tc * 128;
  const int kvsel = wave >> 1;
  const int rowb  = (wave & 1) << 3;
  const unsigned short* gsrc = qkv + (size_t)(t0 + rowb + (lane >> 3)) * NQKV
                               + 512 + (kvsel << 9) + h * 64 + ((lane & 7) << 3);
  unsigned short* ldst = (kvsel ? vb16 : kb16) + (rowb << 6);

  for (int tt = 0; tt < 128; tt += 16) {
    __syncthreads();
    gl_lds16(gsrc + (size_t)tt * NQKV, ldst);
    __syncthreads();
#pragma unroll
    for (int t = 0; t < 16; t++) {
      const ushort4 kr = *(const ushort4*)&kb16[t * 64 + (tx << 2)];
      const ushort4 vr = *(const ushort4*)&vb16[t * 64 + (ty << 2)];
      floatx4 kf;
      kf.x = b2f(kr.x); kf.y = b2f(kr.y); kf.z = b2f(kr.z); kf.w = b2f(kr.w);
      acc[0] += b2f(vr.x) * kf;
      acc[1] += b2f(vr.y) * kf;
      acc[2] += b2f(vr.z) * kf;
      acc[3] += b2f(vr.w) * kf;
    }
    const ushort4 kk = *(const ushort4*)&kb16[ty * 64 + (tx << 2)];
    ksacc.x += b2f(kk.x); ksacc.y += b2f(kk.y);
    ksacc.z += b2f(kk.z); ksacc.w += b2f(kk.w);
  }
  __syncthreads();
  *(floatx4*)&ksred[ty * 64 + (tx << 2)] = ksacc;
  __syncthreads();

  float* pg = part + ((size_t)(tc * 32 + bh) << 12) + (size_t)(ty << 2) * 64 + (tx << 2);
#pragma unroll
  for (int i = 0; i < 4; i++)
    *(floatx4*)(pg + i * 64) = acc[i];

  if (tid < 64) {
    float s = 0.f;
    for (int t2 = 0; t2 < 16; t2++) s += ksred[t2 * 64 + tid];
    ksp[(tc * 32 + bh) * 64 + tid] = s;
  }
}

// ---------------- reduce partials -> ctxb bf16 [bh][80][64] ----------------
__global__ __launch_bounds__(256) void ctx_reduce(const float* __restrict__ part,
                                                  const float* __restrict__ ksp,
                                                  unsigned short* __restrict__ ctxb) {
  const int bh = blockIdx.x / 5, g = blockIdx.x % 5;
  const int row = (g << 4) + (threadIdx.x >> 4);
  const int d0  = (threadIdx.x & 15) << 2;
  floatx4 s = {0.f, 0.f, 0.f, 0.f};
  if (row < 64) {
    const float* p = part + ((size_t)bh << 12) + row * 64 + d0;
    for (int c = 0; c < 32; c++)
      s += *(const floatx4*)(p + ((size_t)c << 17));
  } else if (row == 64) {
    const float* p = ksp + bh * 64 + d0;
    for (int c = 0; c < 32; c++)
      s += *(const floatx4*)(p + (c << 11));
  }
  ushort4 o;
  o.x = f2b(s.x); o.y = f2b(s.y); o.z = f2b(s.z); o.w = f2b(s.w);
  *(ushort4*)&ctxb[(size_t)bh * 5120 + (row << 6) + d0] = o;
}

// ---------------- attn_out via MFMA, fragment loads straight from global ----------------
__global__ __launch_bounds__(256) void attn_out(const unsigned short* __restrict__ qkv,
                                                const unsigned short* __restrict__ ctxb,
                                                unsigned short* __restrict__ opre) {
  const int tc = blockIdx.x >> 5;      // bh-fast
  const int bh = blockIdx.x & 31;
  const int b = bh >> 3, h = bh & 7;
  const int t0 = b * TT + (tc << 6);
  __shared__ unsigned short os[64 * 72];
  const int tid = threadIdx.x;
  const int lane = tid & 63, w = tid >> 6, quad = lane >> 4, lr = lane & 15;

  floatx4 acc[5] = {};
  const unsigned short* qbase = qkv + (size_t)(t0 + (w << 4) + lr) * NQKV + h * 64 + (quad << 3);
  const unsigned short* cbase = ctxb + (size_t)bh * 5120 + (quad << 3);
#pragma unroll
  for (int k2 = 0; k2 < 2; k2++) {
    const frag8 bfr = *(const frag8*)(qbase + (k2 << 5));
#pragma unroll
    for (int et = 0; et < 5; et++) {
      const frag8 afr = *(const frag8*)(cbase + (((et << 4) + lr) << 6) + (k2 << 5));
      acc[et] = __builtin_amdgcn_mfma_f32_16x16x32_bf16(afr, bfr, acc[et], 0, 0, 0);
    }
  }
  const float dinv = 1.f / __shfl(acc[4][0], lr);

  const int trow = (w << 4) + lr;
#pragma unroll
  for (int et = 0; et < 4; et++)
#pragma unroll
    for (int r = 0; r < 4; r++)
      os[trow * 72 + (et << 4) + (quad << 2) + r] = f2b(acc[et][r] * dinv);
  __syncthreads();

  for (int i = tid; i < 512; i += 256) {
    const int row = i >> 3, c8 = (i & 7) << 3;
    const uint4 qraw = *(const uint4*)&qkv[(size_t)(t0 + row) * NQKV + h * 64 + c8];
    const uint4 ov   = *(const uint4*)&os[row * 72 + c8];
    const unsigned short* qp = (const unsigned short*)&qraw;
    const unsigned short* op = (const unsigned short*)&ov;
    unsigned short o8[8];
#pragma unroll
    for (int jj = 0; jj < 8; jj++) o8[jj] = f2b(b2f(op[jj]) + b2f(qp[jj]));
    *(uint4*)&opre[(size_t)(t0 + row) * KDIM + h * 64 + c8] = *(const uint4*)o8;
  }
}

// ---------------- final GEMM: 128x128, fp32 out ----------------
__global__ __launch_bounds__(256, 2) void gemm_out(
    const unsigned short* __restrict__ A,
    const unsigned short* __restrict__ Bm,
    const float* __restrict__ bias,
    float* __restrict__ C)
{
  __shared__ unsigned short sh[2 * 128 * 32];
  unsigned short* As = sh;
  unsigned short* Bs = sh + 128 * 32;
  const int tid  = threadIdx.x;
  const int wave = tid >> 6;
  const int lane = tid & 63;
  const int quad = lane >> 4;
  const int lr   = lane & 15;
  const int bid  = ((blockIdx.x & 7) * 64) + (blockIdx.x >> 3);   // grid 512
  const int bn   = (bid & 3) << 7;
  const int bm   = (bid >> 2) << 7;
  const int wm   = (wave >> 1) << 6;
  const int wn   = (wave & 1) << 6;

  floatx4 acc[4][4] = {};

  const int srow = tid >> 2;
  const int scol = (tid & 3) << 3;
  const unsigned short* Ag = A + (size_t)(bm + srow) * 512 + scol;
  const unsigned short* Bg = Bm + (size_t)(bn + srow) * 512 + scol;
  unsigned short* Al = As + (wave << 9);
  unsigned short* Bl = Bs + (wave << 9);

  for (int k0 = 0; k0 < 512; k0 += 32) {
    __syncthreads();
    gl_lds16(Ag + k0, Al);
    gl_lds16(Ag + 64 * 512 + k0, Al + 64 * 32);
    gl_lds16(Bg + k0, Bl);
    gl_lds16(Bg + 64 * 512 + k0, Bl + 64 * 32);
    __syncthreads();

    frag8 af[4], bf[4];
#pragma unroll
    for (int i = 0; i < 4; i++)
      af[i] = *(const frag8*)&As[(wm + (i << 4) + lr) * 32 + (quad << 3)];
#pragma unroll
    for (int j = 0; j < 4; j++)
      bf[j] = *(const frag8*)&Bs[(wn + (j << 4) + lr) * 32 + (quad << 3)];
#pragma unroll
    for (int i = 0; i < 4; i++)
#pragma unroll
      for (int j = 0; j < 4; j++)
        acc[i][j] = __builtin_amdgcn_mfma_f32_16x16x32_bf16(af[i], bf[j], acc[i][j], 0, 0, 0);
  }

  const int crow0 = bm + wm + (quad << 2);
  const int ccol0 = bn + wn + lr;
#pragma unroll
  for (int j = 0; j < 4; j++) {
    const int col = ccol0 + (j << 4);
    const float bv = bias[col];
#pragma unroll
    for (int i = 0; i < 4; i++) {
      const int row = crow0 + (i << 4);
#pragma unroll
      for (int r = 0; r < 4; r++)
        C[(size_t)(row + r) * 512 + col] = acc[i][j][r] + bv;
    }
  }
}

// ---------------- launch ----------------
extern "C" void kernel_launch(void* const* d_in, const int* in_sizes, int n_in,
                              void* d_out, int out_size, void* d_ws, size_t ws_size,
                              hipStream_t stream) {
  (void)in_sizes; (void)n_in; (void)out_size; (void)ws_size;
  const float* x  = (const float*)d_in[0];
  const float* Wq = (const float*)d_in[1];
  const float* bq = (const float*)d_in[2];
  const float* Wk = (const float*)d_in[3];
  const float* bk = (const float*)d_in[4];
  const float* Wv = (const float*)d_in[5];
  const float* bv = (const float*)d_in[6];
  const float* Wp = (const float*)d_in[7];
  const float* bp = (const float*)d_in[8];

  char* w = (char*)d_ws;
  unsigned short* xb   = (unsigned short*)w; w += (size_t)NTOK * KDIM * 2;   // 16 MB
  float* part          = (float*)xb;         // alias: xb dead after qkv GEMM
  unsigned short* wqkv = (unsigned short*)w; w += (size_t)NQKV * KDIM * 2;   // 1.5 MB
  unsigned short* wp   = (unsigned short*)w; w += (size_t)KDIM * KDIM * 2;   // 0.5 MB
  float* bias_qkv      = (float*)w;          w += (size_t)NQKV * 4;          // 6 KB
  float* ksp           = (float*)w;          w += (size_t)1024 * 64 * 4;     // 256 KB
  unsigned short* ctxb = (unsigned short*)w; w += (size_t)32 * 80 * 64 * 2;  // 320 KB
  unsigned short* qkv  = (unsigned short*)w; w += (size_t)NTOK * NQKV * 2;   // 48 MB
  unsigned short* opre = (unsigned short*)w; w += (size_t)NTOK * KDIM * 2;   // 16 MB

  cvt_x<<<8192, 256, 0, stream>>>(x, xb);
  prep_weights<<<4102, 256, 0, stream>>>(Wq, Wk, Wv, Wp, bq, bk, bv, wqkv, wp, bias_qkv);
  gemm_qkv<<<768, 256, 0, stream>>>(xb, wqkv, bias_qkv, qkv);
  kv_context<<<1024, 256, 0, stream>>>(qkv, part, ksp);
  ctx_reduce<<<160, 256, 0, stream>>>(part, ksp, ctxb);
  attn_out<<<2048, 256, 0, stream>>>(qkv, ctxb, opre);
  gemm_out<<<512, 256, 0, stream>>>(opre, wp, bp, (float*)d_out);
}

// Round 5
// 205.107 us; speedup vs baseline: 1.0019x; 1.0019x over previous
//
#include <hip/hip_runtime.h>

#define NTOK  16384   // B*T
#define KDIM  512
#define NQKV  1536
#define TT    4096

using frag8   = __attribute__((ext_vector_type(8))) short;
using floatx4 = __attribute__((ext_vector_type(4))) float;

__device__ __forceinline__ unsigned short f2b(float f) {
  union { float f; unsigned u; } v; v.f = f;
  unsigned r = v.u + 0x7fffu + ((v.u >> 16) & 1u);
  return (unsigned short)(r >> 16);
}
__device__ __forceinline__ float b2f(unsigned short s) {
  union { unsigned u; float f; } v; v.u = ((unsigned)s) << 16; return v.f;
}

__device__ __forceinline__ void gl_lds16(const void* g, void* l) {
  __builtin_amdgcn_global_load_lds((__attribute__((address_space(1))) const void*)g,
                                   (__attribute__((address_space(3))) void*)l,
                                   16, 0, 0);
}

// ---------------- convert kernels ----------------
__global__ __launch_bounds__(256) void cvt_x(const float* __restrict__ x,
                                             unsigned short* __restrict__ xb) {
  const size_t i = (size_t)blockIdx.x * 256 + threadIdx.x;
  const float4 v = ((const float4*)x)[i];
  ushort4 o;
  o.x = f2b(v.x); o.y = f2b(v.y); o.z = f2b(v.z); o.w = f2b(v.w);
  ((ushort4*)xb)[i] = o;
}

__global__ __launch_bounds__(256) void prep_weights(
    const float* __restrict__ Wq, const float* __restrict__ Wk,
    const float* __restrict__ Wv, const float* __restrict__ Wp,
    const float* __restrict__ bq, const float* __restrict__ bk,
    const float* __restrict__ bv,
    unsigned short* __restrict__ wqkv, unsigned short* __restrict__ wp,
    float* __restrict__ bias_qkv) {
  const int idx = blockIdx.x * 256 + threadIdx.x;
  if (idx < 786432) {                       // 1536*512
    const int m = idx >> 9, i = idx & 511;
    const float* W = (m < 512) ? Wq : ((m < 1024) ? Wk : Wv);
    wqkv[idx] = f2b(W[(m & 511) * 512 + i]);
    return;
  }
  const int j = idx - 786432;
  if (j < 262144) { wp[j] = f2b(Wp[j]); return; }
  const int c = j - 262144;
  if (c < 1536)
    bias_qkv[c] = (c < 512) ? bq[c] : ((c < 1024) ? bk[c - 512] : bv[c - 1024]);
}

// ---------------- m97-style bf16 GEMM, B^T input, XCD-swizzled, 4 blocks/CU ----------------
// SOFT=1: fused per-head softmax on q/k regions, coalesced bf16 store via LDS repack.
// SOFT=0: plain fp32 store + bias.
template<int SOFT>
__global__ __launch_bounds__(256, 4) void gemm_bt(
    const unsigned short* __restrict__ A,
    const unsigned short* __restrict__ Bm,
    const float* __restrict__ bias,
    void* __restrict__ C,
    int M, int N, int K, int ldc)
{
  __shared__ unsigned short sh[2 * 128 * 32];
  unsigned short* As = sh;
  unsigned short* Bs = sh + 128 * 32;
  const int tid  = threadIdx.x;
  const int wave = tid >> 6;
  const int lane = tid & 63;
  const int quad = lane >> 4;
  const int lr   = lane & 15;
  // XCD swizzle: keep all n-tiles of an m-tile on one XCD (L2 A-reuse)
  const int bid  = ((blockIdx.x & 7) * (gridDim.x >> 3)) + (blockIdx.x >> 3);
  const int nt   = N >> 7;
  const int bn   = (bid % nt) << 7;
  const int bm   = (bid / nt) << 7;
  const int half = wave >> 1;
  const int wm   = half << 6;
  const int wn   = (wave & 1) << 6;

  floatx4 acc[4][4] = {};

  const int srow = tid >> 2;
  const int scol = (tid & 3) << 3;
  const unsigned short* Ag = A + (size_t)(bm + srow) * K + scol;
  const unsigned short* Bg = Bm + (size_t)(bn + srow) * K + scol;
  unsigned short* Al = As + (wave << 9);
  unsigned short* Bl = Bs + (wave << 9);

  for (int k0 = 0; k0 < K; k0 += 32) {
    __syncthreads();
    gl_lds16(Ag + k0, Al);
    gl_lds16(Ag + (size_t)64 * K + k0, Al + 64 * 32);
    gl_lds16(Bg + k0, Bl);
    gl_lds16(Bg + (size_t)64 * K + k0, Bl + 64 * 32);
    __syncthreads();

    frag8 af[4], bf[4];
#pragma unroll
    for (int i = 0; i < 4; i++)
      af[i] = *(const frag8*)&As[(wm + (i << 4) + lr) * 32 + (quad << 3)];
#pragma unroll
    for (int j = 0; j < 4; j++)
      bf[j] = *(const frag8*)&Bs[(wn + (j << 4) + lr) * 32 + (quad << 3)];
#pragma unroll
    for (int i = 0; i < 4; i++)
#pragma unroll
      for (int j = 0; j < 4; j++)
        acc[i][j] = __builtin_amdgcn_mfma_f32_16x16x32_bf16(af[i], bf[j], acc[i][j], 0, 0, 0);
  }

  // epilogue: C/D layout col=lane&15, row=quad*4+reg
  const int ccol0 = bn + wn + lr;

#pragma unroll
  for (int j = 0; j < 4; j++) {
    const float bv = bias[ccol0 + (j << 4)];
#pragma unroll
    for (int i = 0; i < 4; i++)
#pragma unroll
      for (int r = 0; r < 4; r++)
        acc[i][j][r] += bv;
  }

  if (SOFT) {
    const int region = (bn + wn) >> 9;   // 0=q, 1=k, 2=v (wave-uniform)
    if (region < 2) {
#pragma unroll
      for (int i = 0; i < 4; i++)
#pragma unroll
        for (int r = 0; r < 4; r++) {
          float e0 = __expf(acc[i][0][r]);
          float e1 = __expf(acc[i][1][r]);
          float e2 = __expf(acc[i][2][r]);
          float e3 = __expf(acc[i][3][r]);
          float s = e0 + e1 + e2 + e3;
          s += __shfl_xor(s, 1);
          s += __shfl_xor(s, 2);
          s += __shfl_xor(s, 4);
          s += __shfl_xor(s, 8);
          const float inv = 1.f / s;
          acc[i][0][r] = e0 * inv; acc[i][1][r] = e1 * inv;
          acc[i][2][r] = e2 * inv; acc[i][3][r] = e3 * inv;
        }
    }
    // coalesced bf16 store: repack 64-row halves through the (dead) staging LDS
    unsigned short* os = sh;             // 64 x 128 bf16 = 16 KB
#pragma unroll
    for (int p = 0; p < 2; p++) {
      __syncthreads();
      if (half == p) {
#pragma unroll
        for (int i = 0; i < 4; i++)
#pragma unroll
          for (int j = 0; j < 4; j++)
#pragma unroll
            for (int r = 0; r < 4; r++)
              os[((i << 4) + (quad << 2) + r) * 128 + wn + (j << 4) + lr] = f2b(acc[i][j][r]);
      }
      __syncthreads();
#pragma unroll
      for (int it = 0; it < 4; it++) {
        const int idx = (it << 8) + tid;   // 1024 uint4 total
        const int row = idx >> 4;
        const int c8  = (idx & 15) << 3;
        *(uint4*)((unsigned short*)C + (size_t)(bm + (p << 6) + row) * ldc + bn + c8) =
            *(const uint4*)&os[row * 128 + c8];
      }
    }
  } else {
    const int crow0 = bm + wm + (quad << 2);
#pragma unroll
    for (int j = 0; j < 4; j++) {
      const int col = ccol0 + (j << 4);
#pragma unroll
      for (int i = 0; i < 4; i++) {
        const int row = crow0 + (i << 4);
#pragma unroll
        for (int r = 0; r < 4; r++)
          ((float*)C)[(size_t)(row + r) * ldc + col] = acc[i][j][r];
      }
    }
  }
}

// ---------------- partial ctxT[e][d] + ksum partial per (chunk,bh) ----------------
// Barrier-free: direct global ushort4 reads (L1/L2-served, 16x lane reuse), rank-1 VALU update.
__global__ __launch_bounds__(256) void kv_context(const unsigned short* __restrict__ qkv,
                                                  float* __restrict__ part,
                                                  float* __restrict__ ksp) {
  const int tc  = blockIdx.x & 31;     // tc-fast: same-bh blocks spread over XCDs
  const int bh  = blockIdx.x >> 5;
  const int b   = bh >> 3, h = bh & 7;
  const int tid = threadIdx.x;
  const int ty = tid >> 4, tx = tid & 15;
  floatx4 acc[4] = {};
  floatx4 ksacc = {0.f, 0.f, 0.f, 0.f};

  const int t0 = b * TT + tc * 128;
  const unsigned short* kp = qkv + (size_t)t0 * NQKV + 512 + h * 64 + (tx << 2);
  const unsigned short* vp = qkv + (size_t)t0 * NQKV + 1024 + h * 64 + (ty << 2);

#pragma unroll 8
  for (int t = 0; t < 128; t++) {
    const ushort4 kr = *(const ushort4*)(kp + (size_t)t * NQKV);
    const ushort4 vr = *(const ushort4*)(vp + (size_t)t * NQKV);
    floatx4 kf;
    kf.x = b2f(kr.x); kf.y = b2f(kr.y); kf.z = b2f(kr.z); kf.w = b2f(kr.w);
    acc[0] += b2f(vr.x) * kf;
    acc[1] += b2f(vr.y) * kf;
    acc[2] += b2f(vr.z) * kf;
    acc[3] += b2f(vr.w) * kf;
    ksacc += kf;
  }

  float* pg = part + ((size_t)(tc * 32 + bh) << 12) + (size_t)(ty << 2) * 64 + (tx << 2);
#pragma unroll
  for (int i = 0; i < 4; i++)
    *(floatx4*)(pg + i * 64) = acc[i];

  if (ty == 0)   // ksacc identical across ty; one writer per d-slice
    *(floatx4*)&ksp[(tc * 32 + bh) * 64 + (tx << 2)] = ksacc;
}

// ---------------- reduce partials -> ctxb bf16 [bh][80][64] ----------------
// rows 0-63 = ctxT, row 64 = ksum, rows 65-79 = 0
__global__ __launch_bounds__(256) void ctx_reduce(const float* __restrict__ part,
                                                  const float* __restrict__ ksp,
                                                  unsigned short* __restrict__ ctxb) {
  const int bh = blockIdx.x / 5, g = blockIdx.x % 5;
  const int row = (g << 4) + (threadIdx.x >> 4);
  const int d0  = (threadIdx.x & 15) << 2;
  floatx4 s = {0.f, 0.f, 0.f, 0.f};
  if (row < 64) {
    const float* p = part + ((size_t)bh << 12) + row * 64 + d0;
    for (int c = 0; c < 32; c++)
      s += *(const floatx4*)(p + ((size_t)c << 17));
  } else if (row == 64) {
    const float* p = ksp + bh * 64 + d0;
    for (int c = 0; c < 32; c++)
      s += *(const floatx4*)(p + (c << 11));
  }
  ushort4 o;
  o.x = f2b(s.x); o.y = f2b(s.y); o.z = f2b(s.z); o.w = f2b(s.w);
  *(ushort4*)&ctxb[(size_t)bh * 5120 + (row << 6) + d0] = o;
}

// ---------------- attn_out via MFMA: outT[e][t] = ctxT[e][:]·q'[t][:] ----------------
__global__ __launch_bounds__(256) void attn_out(const unsigned short* __restrict__ qkv,
                                                const unsigned short* __restrict__ ctxb,
                                                unsigned short* __restrict__ opre) {
  const int tc = blockIdx.x >> 5;      // bh-fast
  const int bh = blockIdx.x & 31;
  const int b = bh >> 3, h = bh & 7;
  const int t0 = b * TT + (tc << 6);
  __shared__ unsigned short sh[144 * 72];   // qs[64][72] | cs[80][72] (cs reused as os)
  unsigned short* qs = sh;
  unsigned short* cs = sh + 64 * 72;
  unsigned short* os = cs;
  const int tid = threadIdx.x;

  for (int i = tid; i < 512; i += 256) {
    const int row = i >> 3, c8 = (i & 7) << 3;
    *(uint4*)&qs[row * 72 + c8] =
        *(const uint4*)&qkv[(size_t)(t0 + row) * NQKV + h * 64 + c8];
  }
  for (int i = tid; i < 640; i += 256) {
    const int row = i >> 3, c8 = (i & 7) << 3;
    *(uint4*)&cs[row * 72 + c8] =
        *(const uint4*)&ctxb[(size_t)bh * 5120 + (row << 6) + c8];
  }
  __syncthreads();

  const int lane = tid & 63, w = tid >> 6, quad = lane >> 4, lr = lane & 15;
  floatx4 acc[5] = {};
#pragma unroll
  for (int k2 = 0; k2 < 2; k2++) {
    const int d0 = (k2 << 5) + (quad << 3);
    const frag8 bf = *(const frag8*)&qs[((w << 4) + lr) * 72 + d0];
#pragma unroll
    for (int et = 0; et < 5; et++) {
      const frag8 af = *(const frag8*)&cs[(et * 16 + lr) * 72 + d0];
      acc[et] = __builtin_amdgcn_mfma_f32_16x16x32_bf16(af, bf, acc[et], 0, 0, 0);
    }
  }
  const float dinv = 1.f / __shfl(acc[4][0], lr);
  __syncthreads();                      // done reading cs; reuse as os

  const int trow = (w << 4) + lr;
#pragma unroll
  for (int et = 0; et < 4; et++)
#pragma unroll
    for (int r = 0; r < 4; r++) {
      const int e = et * 16 + (quad << 2) + r;
      const float qv = b2f(qs[trow * 72 + e]);
      os[trow * 72 + e] = f2b(acc[et][r] * dinv + qv);
    }
  __syncthreads();

  for (int i = tid; i < 512; i += 256) {
    const int row = i >> 3, c8 = (i & 7) << 3;
    *(uint4*)&opre[(size_t)(t0 + row) * KDIM + h * 64 + c8] = *(const uint4*)&os[row * 72 + c8];
  }
}

// ---------------- launch ----------------
extern "C" void kernel_launch(void* const* d_in, const int* in_sizes, int n_in,
                              void* d_out, int out_size, void* d_ws, size_t ws_size,
                              hipStream_t stream) {
  (void)in_sizes; (void)n_in; (void)out_size; (void)ws_size;
  const float* x  = (const float*)d_in[0];
  const float* Wq = (const float*)d_in[1];
  const float* bq = (const float*)d_in[2];
  const float* Wk = (const float*)d_in[3];
  const float* bk = (const float*)d_in[4];
  const float* Wv = (const float*)d_in[5];
  const float* bv = (const float*)d_in[6];
  const float* Wp = (const float*)d_in[7];
  const float* bp = (const float*)d_in[8];

  char* w = (char*)d_ws;
  unsigned short* xb   = (unsigned short*)w; w += (size_t)NTOK * KDIM * 2;   // 16 MB
  float* part          = (float*)xb;         // alias: xb dead after qkv GEMM
  unsigned short* wqkv = (unsigned short*)w; w += (size_t)NQKV * KDIM * 2;   // 1.5 MB
  unsigned short* wp   = (unsigned short*)w; w += (size_t)KDIM * KDIM * 2;   // 0.5 MB
  float* bias_qkv      = (float*)w;          w += (size_t)NQKV * 4;          // 6 KB
  float* ksp           = (float*)w;          w += (size_t)1024 * 64 * 4;     // 256 KB
  unsigned short* ctxb = (unsigned short*)w; w += (size_t)32 * 80 * 64 * 2;  // 320 KB
  unsigned short* qkv  = (unsigned short*)w; w += (size_t)NTOK * NQKV * 2;   // 48 MB
  unsigned short* opre = (unsigned short*)w; w += (size_t)NTOK * KDIM * 2;   // 16 MB

  cvt_x<<<8192, 256, 0, stream>>>(x, xb);
  prep_weights<<<4102, 256, 0, stream>>>(Wq, Wk, Wv, Wp, bq, bk, bv, wqkv, wp, bias_qkv);
  gemm_bt<1><<<(NTOK / 128) * (NQKV / 128), 256, 0, stream>>>(
      xb, wqkv, bias_qkv, qkv, NTOK, NQKV, KDIM, NQKV);
  kv_context<<<1024, 256, 0, stream>>>(qkv, part, ksp);
  ctx_reduce<<<160, 256, 0, stream>>>(part, ksp, ctxb);
  attn_out<<<2048, 256, 0, stream>>>(qkv, ctxb, opre);
  gemm_bt<0><<<(NTOK / 128) * (KDIM / 128), 256, 0, stream>>>(
      opre, wp, bp, d_out, NTOK, KDIM, KDIM, KDIM);
}

// Round 6
// 177.798 us; speedup vs baseline: 1.1558x; 1.1536x over previous
//
#include <hip/hip_runtime.h>

#define NTOK  16384   // B*T
#define KDIM  512
#define NQKV  1536
#define TT    4096

using frag8   = __attribute__((ext_vector_type(8))) short;
using floatx4 = __attribute__((ext_vector_type(4))) float;

__device__ __forceinline__ unsigned short f2b(float f) {
  union { float f; unsigned u; } v; v.f = f;
  unsigned r = v.u + 0x7fffu + ((v.u >> 16) & 1u);
  return (unsigned short)(r >> 16);
}
__device__ __forceinline__ float b2f(unsigned short s) {
  union { unsigned u; float f; } v; v.u = ((unsigned)s) << 16; return v.f;
}
__device__ __forceinline__ float blo(unsigned w) {
  union { unsigned u; float f; } v; v.u = w << 16; return v.f;
}
__device__ __forceinline__ float bhi(unsigned w) {
  union { unsigned u; float f; } v; v.u = w & 0xffff0000u; return v.f;
}

__device__ __forceinline__ void gl_lds16(const void* g, void* l) {
  __builtin_amdgcn_global_load_lds((__attribute__((address_space(1))) const void*)g,
                                   (__attribute__((address_space(3))) void*)l,
                                   16, 0, 0);
}

// ---------------- fused convert: x -> bf16, weights -> bf16, bias concat ----------------
__global__ __launch_bounds__(256) void cvt_all(
    const float* __restrict__ x,
    const float* __restrict__ Wq, const float* __restrict__ Wk,
    const float* __restrict__ Wv, const float* __restrict__ Wp,
    const float* __restrict__ bq, const float* __restrict__ bk,
    const float* __restrict__ bv,
    unsigned short* __restrict__ xb,
    unsigned short* __restrict__ wqkv, unsigned short* __restrict__ wp,
    float* __restrict__ bias_qkv) {
  const int blk = blockIdx.x;
  if (blk < 8192) {                          // x: 8.4M floats, float4 per thread
    const size_t i = (size_t)blk * 256 + threadIdx.x;
    const float4 v = ((const float4*)x)[i];
    ushort4 o;
    o.x = f2b(v.x); o.y = f2b(v.y); o.z = f2b(v.z); o.w = f2b(v.w);
    ((ushort4*)xb)[i] = o;
    return;
  }
  const int idx = (blk - 8192) * 256 + threadIdx.x;
  if (idx < 786432) {                       // 1536*512
    const int m = idx >> 9, i = idx & 511;
    const float* W = (m < 512) ? Wq : ((m < 1024) ? Wk : Wv);
    wqkv[idx] = f2b(W[(m & 511) * 512 + i]);
    return;
  }
  const int j = idx - 786432;
  if (j < 262144) { wp[j] = f2b(Wp[j]); return; }
  const int c = j - 262144;
  if (c < 1536)
    bias_qkv[c] = (c < 512) ? bq[c] : ((c < 1024) ? bk[c - 512] : bv[c - 1024]);
}

// ---------------- bf16 GEMM, B^T input, XCD-swizzled, BK=64 + XOR LDS swizzle ----------------
// SOFT=1: fused per-head softmax on q/k regions, coalesced bf16 store via LDS repack.
// SOFT=0: plain fp32 store + bias.
template<int SOFT>
__global__ __launch_bounds__(256, 2) void gemm_bt(
    const unsigned short* __restrict__ A,
    const unsigned short* __restrict__ Bm,
    const float* __restrict__ bias,
    void* __restrict__ C,
    int M, int N, int K, int ldc)
{
  __shared__ unsigned short sh[2 * 128 * 64];   // 32 KB
  unsigned short* As = sh;
  unsigned short* Bs = sh + 128 * 64;
  const int tid  = threadIdx.x;
  const int wave = tid >> 6;
  const int lane = tid & 63;
  const int quad = lane >> 4;
  const int lr   = lane & 15;
  const int sw7  = lr & 7;
  // XCD swizzle: keep all n-tiles of an m-tile on one XCD (L2 A-reuse)
  const int bid  = ((blockIdx.x & 7) * (gridDim.x >> 3)) + (blockIdx.x >> 3);
  const int nt   = N >> 7;
  const int bn   = (bid % nt) << 7;
  const int bm   = (bid / nt) << 7;
  const int half = wave >> 1;
  const int wm   = half << 6;
  const int wn   = (wave & 1) << 6;

  floatx4 acc[4][4] = {};

  // staging: thread t -> row = t/8 (+32/round), global 16B chunk = (t&7) ^ (row&7)
  // gl_lds16 writes lane l -> ldsbase + 16*l, so LDS chunk (t&7) of row holds
  // global chunk (t&7)^(row&7): an XOR swizzle that kills the 128B-row bank alias.
  const int srow = tid >> 3;
  const int scol = ((tid & 7) ^ ((tid >> 3) & 7)) << 3;
  const unsigned short* Ag = A + (size_t)(bm + srow) * K + scol;
  const unsigned short* Bg = Bm + (size_t)(bn + srow) * K + scol;
  unsigned short* Al = As + (wave << 9);   // wave*512 shorts = 1 KB
  unsigned short* Bl = Bs + (wave << 9);

  for (int k0 = 0; k0 < K; k0 += 64) {
    __syncthreads();
    gl_lds16(Ag + k0,                    Al);
    gl_lds16(Ag + (size_t)32 * K + k0,   Al + 2048);
    gl_lds16(Ag + (size_t)64 * K + k0,   Al + 4096);
    gl_lds16(Ag + (size_t)96 * K + k0,   Al + 6144);
    gl_lds16(Bg + k0,                    Bl);
    gl_lds16(Bg + (size_t)32 * K + k0,   Bl + 2048);
    gl_lds16(Bg + (size_t)64 * K + k0,   Bl + 4096);
    gl_lds16(Bg + (size_t)96 * K + k0,   Bl + 6144);
    __syncthreads();

#pragma unroll
    for (int kk = 0; kk < 2; kk++) {
      const int coff = ((((kk << 2) + quad) ^ sw7) << 3);
      frag8 af[4], bf[4];
#pragma unroll
      for (int i = 0; i < 4; i++)
        af[i] = *(const frag8*)&As[(wm + (i << 4) + lr) * 64 + coff];
#pragma unroll
      for (int j = 0; j < 4; j++)
        bf[j] = *(const frag8*)&Bs[(wn + (j << 4) + lr) * 64 + coff];
#pragma unroll
      for (int i = 0; i < 4; i++)
#pragma unroll
        for (int j = 0; j < 4; j++)
          acc[i][j] = __builtin_amdgcn_mfma_f32_16x16x32_bf16(af[i], bf[j], acc[i][j], 0, 0, 0);
    }
  }

  // epilogue: C/D layout col=lane&15, row=quad*4+reg
  const int ccol0 = bn + wn + lr;

#pragma unroll
  for (int j = 0; j < 4; j++) {
    const float bv = bias[ccol0 + (j << 4)];
#pragma unroll
    for (int i = 0; i < 4; i++)
#pragma unroll
      for (int r = 0; r < 4; r++)
        acc[i][j][r] += bv;
  }

  if (SOFT) {
    const int region = (bn + wn) >> 9;   // 0=q, 1=k, 2=v (wave-uniform)
    if (region < 2) {
#pragma unroll
      for (int i = 0; i < 4; i++)
#pragma unroll
        for (int r = 0; r < 4; r++) {
          float e0 = __expf(acc[i][0][r]);
          float e1 = __expf(acc[i][1][r]);
          float e2 = __expf(acc[i][2][r]);
          float e3 = __expf(acc[i][3][r]);
          float s = e0 + e1 + e2 + e3;
          s += __shfl_xor(s, 1);
          s += __shfl_xor(s, 2);
          s += __shfl_xor(s, 4);
          s += __shfl_xor(s, 8);
          const float inv = 1.f / s;
          acc[i][0][r] = e0 * inv; acc[i][1][r] = e1 * inv;
          acc[i][2][r] = e2 * inv; acc[i][3][r] = e3 * inv;
        }
    }
    // coalesced bf16 store: repack 64-row halves through the (dead) staging LDS
    unsigned short* os = sh;             // 64 x 128 bf16 = 16 KB
#pragma unroll
    for (int p = 0; p < 2; p++) {
      __syncthreads();
      if (half == p) {
#pragma unroll
        for (int i = 0; i < 4; i++)
#pragma unroll
          for (int j = 0; j < 4; j++)
#pragma unroll
            for (int r = 0; r < 4; r++)
              os[((i << 4) + (quad << 2) + r) * 128 + wn + (j << 4) + lr] = f2b(acc[i][j][r]);
      }
      __syncthreads();
#pragma unroll
      for (int it = 0; it < 4; it++) {
        const int idx = (it << 8) + tid;   // 1024 uint4 total
        const int row = idx >> 4;
        const int c8  = (idx & 15) << 3;
        *(uint4*)((unsigned short*)C + (size_t)(bm + (p << 6) + row) * ldc + bn + c8) =
            *(const uint4*)&os[row * 128 + c8];
      }
    }
  } else {
    const int crow0 = bm + wm + (quad << 2);
#pragma unroll
    for (int j = 0; j < 4; j++) {
      const int col = ccol0 + (j << 4);
#pragma unroll
      for (int i = 0; i < 4; i++) {
        const int row = crow0 + (i << 4);
#pragma unroll
        for (int r = 0; r < 4; r++)
          ((float*)C)[(size_t)(row + r) * ldc + col] = acc[i][j][r];
      }
    }
  }
}

// ---------------- partial ctxT[e][d] + ksum partial per (chunk,bh) ----------------
// R3-proven LDS-staged version; unpack via explicit floatx4 stores (bank-conflict fix).
__global__ __launch_bounds__(256) void kv_context(const unsigned short* __restrict__ qkv,
                                                  float* __restrict__ part,
                                                  float* __restrict__ ksp) {
  const int bid = blockIdx.x;          // bh(32) x tc(32), tc-fast
  const int tc  = bid & 31;
  const int bh  = bid >> 5;
  const int b   = bh >> 3, h = bh & 7;
  __shared__ float ks[16 * 64];
  __shared__ float vs[16 * 64];
  const int tid = threadIdx.x;
  const int ty = tid >> 4, tx = tid & 15;
  floatx4 acc[4] = {};
  floatx4 ksacc = {0.f, 0.f, 0.f, 0.f};

  const int si    = tid << 3;
  const int strow = si >> 7;
  const int sw    = si & 127;
  const int t0    = b * TT + tc * 128;
  const unsigned short* gcol = qkv + ((sw < 64) ? (512 + h * 64 + sw)
                                                : (1024 + h * 64 + (sw - 64)));
  float* sdst = (sw < 64) ? &ks[strow * 64 + sw] : &vs[strow * 64 + (sw - 64)];

  for (int tt = 0; tt < 128; tt += 16) {
    __syncthreads();
    const uint4 raw = *(const uint4*)(gcol + (size_t)(t0 + tt + strow) * NQKV);
    const floatx4 f0 = {blo(raw.x), bhi(raw.x), blo(raw.y), bhi(raw.y)};
    const floatx4 f1 = {blo(raw.z), bhi(raw.z), blo(raw.w), bhi(raw.w)};
    *(floatx4*)sdst = f0;
    *(floatx4*)(sdst + 4) = f1;
    __syncthreads();
#pragma unroll
    for (int t = 0; t < 16; t++) {
      const floatx4 vb = *(const floatx4*)&vs[t * 64 + (ty << 2)];  // 4 e's
      const floatx4 kb = *(const floatx4*)&ks[t * 64 + (tx << 2)];  // 4 d's
      acc[0] += vb.x * kb;
      acc[1] += vb.y * kb;
      acc[2] += vb.z * kb;
      acc[3] += vb.w * kb;
    }
    ksacc += *(const floatx4*)&ks[ty * 64 + (tx << 2)];  // token t==ty slice
  }
  // reduce ksacc across ty via LDS (vs is dead)
  __syncthreads();
  *(floatx4*)&vs[ty * 64 + (tx << 2)] = ksacc;
  __syncthreads();

  float* pg = part + ((size_t)(tc * 32 + bh) << 12) + (size_t)(ty << 2) * 64 + (tx << 2);
#pragma unroll
  for (int i = 0; i < 4; i++)
    *(floatx4*)(pg + i * 64) = acc[i];

  if (tid < 64) {
    float s = 0.f;
    for (int t2 = 0; t2 < 16; t2++) s += vs[t2 * 64 + tid];
    ksp[(tc * 32 + bh) * 64 + tid] = s;
  }
}

// ---------------- reduce partials -> ctxb bf16 [bh][80][64] ----------------
// rows 0-63 = ctxT, row 64 = ksum, rows 65-79 = 0
__global__ __launch_bounds__(256) void ctx_reduce(const float* __restrict__ part,
                                                  const float* __restrict__ ksp,
                                                  unsigned short* __restrict__ ctxb) {
  const int bh = blockIdx.x / 5, g = blockIdx.x % 5;
  const int row = (g << 4) + (threadIdx.x >> 4);
  const int d0  = (threadIdx.x & 15) << 2;
  floatx4 s = {0.f, 0.f, 0.f, 0.f};
  if (row < 64) {
    const float* p = part + ((size_t)bh << 12) + row * 64 + d0;
    for (int c = 0; c < 32; c++)
      s += *(const floatx4*)(p + ((size_t)c << 17));
  } else if (row == 64) {
    const float* p = ksp + bh * 64 + d0;
    for (int c = 0; c < 32; c++)
      s += *(const floatx4*)(p + (c << 11));
  }
  ushort4 o;
  o.x = f2b(s.x); o.y = f2b(s.y); o.z = f2b(s.z); o.w = f2b(s.w);
  *(ushort4*)&ctxb[(size_t)bh * 5120 + (row << 6) + d0] = o;
}

// ---------------- attn_out via MFMA: outT[e][t] = ctxT[e][:]·q'[t][:] ----------------
__global__ __launch_bounds__(256) void attn_out(const unsigned short* __restrict__ qkv,
                                                const unsigned short* __restrict__ ctxb,
                                                unsigned short* __restrict__ opre) {
  const int tc = blockIdx.x >> 5;      // bh-fast
  const int bh = blockIdx.x & 31;
  const int b = bh >> 3, h = bh & 7;
  const int t0 = b * TT + (tc << 6);
  __shared__ unsigned short sh[144 * 72];   // qs[64][72] | cs[80][72] (cs reused as os)
  unsigned short* qs = sh;
  unsigned short* cs = sh + 64 * 72;
  unsigned short* os = cs;
  const int tid = threadIdx.x;

  for (int i = tid; i < 512; i += 256) {
    const int row = i >> 3, c8 = (i & 7) << 3;
    *(uint4*)&qs[row * 72 + c8] =
        *(const uint4*)&qkv[(size_t)(t0 + row) * NQKV + h * 64 + c8];
  }
  for (int i = tid; i < 640; i += 256) {
    const int row = i >> 3, c8 = (i & 7) << 3;
    *(uint4*)&cs[row * 72 + c8] =
        *(const uint4*)&ctxb[(size_t)bh * 5120 + (row << 6) + c8];
  }
  __syncthreads();

  const int lane = tid & 63, w = tid >> 6, quad = lane >> 4, lr = lane & 15;
  floatx4 acc[5] = {};
#pragma unroll
  for (int k2 = 0; k2 < 2; k2++) {
    const int d0 = (k2 << 5) + (quad << 3);
    const frag8 bf = *(const frag8*)&qs[((w << 4) + lr) * 72 + d0];
#pragma unroll
    for (int et = 0; et < 5; et++) {
      const frag8 af = *(const frag8*)&cs[(et * 16 + lr) * 72 + d0];
      acc[et] = __builtin_amdgcn_mfma_f32_16x16x32_bf16(af, bf, acc[et], 0, 0, 0);
    }
  }
  const float dinv = 1.f / __shfl(acc[4][0], lr);
  __syncthreads();                      // done reading cs; reuse as os

  const int trow = (w << 4) + lr;
#pragma unroll
  for (int et = 0; et < 4; et++)
#pragma unroll
    for (int r = 0; r < 4; r++) {
      const int e = et * 16 + (quad << 2) + r;
      const float qv = b2f(qs[trow * 72 + e]);
      os[trow * 72 + e] = f2b(acc[et][r] * dinv + qv);
    }
  __syncthreads();

  for (int i = tid; i < 512; i += 256) {
    const int row = i >> 3, c8 = (i & 7) << 3;
    *(uint4*)&opre[(size_t)(t0 + row) * KDIM + h * 64 + c8] = *(const uint4*)&os[row * 72 + c8];
  }
}

// ---------------- launch ----------------
extern "C" void kernel_launch(void* const* d_in, const int* in_sizes, int n_in,
                              void* d_out, int out_size, void* d_ws, size_t ws_size,
                              hipStream_t stream) {
  (void)in_sizes; (void)n_in; (void)out_size; (void)ws_size;
  const float* x  = (const float*)d_in[0];
  const float* Wq = (const float*)d_in[1];
  const float* bq = (const float*)d_in[2];
  const float* Wk = (const float*)d_in[3];
  const float* bk = (const float*)d_in[4];
  const float* Wv = (const float*)d_in[5];
  const float* bv = (const float*)d_in[6];
  const float* Wp = (const float*)d_in[7];
  const float* bp = (const float*)d_in[8];

  char* w = (char*)d_ws;
  unsigned short* xb   = (unsigned short*)w; w += (size_t)NTOK * KDIM * 2;   // 16 MB
  float* part          = (float*)xb;         // alias: xb dead after qkv GEMM
  unsigned short* wqkv = (unsigned short*)w; w += (size_t)NQKV * KDIM * 2;   // 1.5 MB
  unsigned short* wp   = (unsigned short*)w; w += (size_t)KDIM * KDIM * 2;   // 0.5 MB
  float* bias_qkv      = (float*)w;          w += (size_t)NQKV * 4;          // 6 KB
  float* ksp           = (float*)w;          w += (size_t)1024 * 64 * 4;     // 256 KB
  unsigned short* ctxb = (unsigned short*)w; w += (size_t)32 * 80 * 64 * 2;  // 320 KB
  unsigned short* qkv  = (unsigned short*)w; w += (size_t)NTOK * NQKV * 2;   // 48 MB
  unsigned short* opre = (unsigned short*)w; w += (size_t)NTOK * KDIM * 2;   // 16 MB

  cvt_all<<<12294, 256, 0, stream>>>(x, Wq, Wk, Wv, Wp, bq, bk, bv,
                                     xb, wqkv, wp, bias_qkv);
  gemm_bt<1><<<(NTOK / 128) * (NQKV / 128), 256, 0, stream>>>(
      xb, wqkv, bias_qkv, qkv, NTOK, NQKV, KDIM, NQKV);
  kv_context<<<1024, 256, 0, stream>>>(qkv, part, ksp);
  ctx_reduce<<<160, 256, 0, stream>>>(part, ksp, ctxb);
  attn_out<<<2048, 256, 0, stream>>>(qkv, ctxb, opre);
  gemm_bt<0><<<(NTOK / 128) * (KDIM / 128), 256, 0, stream>>>(
      opre, wp, bp, d_out, NTOK, KDIM, KDIM, KDIM);
}

// Round 7
// 177.739 us; speedup vs baseline: 1.1561x; 1.0003x over previous
//
#include <hip/hip_runtime.h>

#define NTOK  16384   // B*T
#define KDIM  512
#define NQKV  1536
#define TT    4096

using frag8   = __attribute__((ext_vector_type(8))) short;
using floatx4 = __attribute__((ext_vector_type(4))) float;

__device__ __forceinline__ unsigned short f2b(float f) {
  union { float f; unsigned u; } v; v.f = f;
  unsigned r = v.u + 0x7fffu + ((v.u >> 16) & 1u);
  return (unsigned short)(r >> 16);
}
__device__ __forceinline__ float b2f(unsigned short s) {
  union { unsigned u; float f; } v; v.u = ((unsigned)s) << 16; return v.f;
}
__device__ __forceinline__ float blo(unsigned w) {
  union { unsigned u; float f; } v; v.u = w << 16; return v.f;
}
__device__ __forceinline__ float bhi(unsigned w) {
  union { unsigned u; float f; } v; v.u = w & 0xffff0000u; return v.f;
}

__device__ __forceinline__ void gl_lds16(const void* g, void* l) {
  __builtin_amdgcn_global_load_lds((__attribute__((address_space(1))) const void*)g,
                                   (__attribute__((address_space(3))) void*)l,
                                   16, 0, 0);
}

// ---------------- fused convert: x -> bf16, weights -> bf16, bias concat ----------------
__global__ __launch_bounds__(256) void cvt_all(
    const float* __restrict__ x,
    const float* __restrict__ Wq, const float* __restrict__ Wk,
    const float* __restrict__ Wv, const float* __restrict__ Wp,
    const float* __restrict__ bq, const float* __restrict__ bk,
    const float* __restrict__ bv,
    unsigned short* __restrict__ xb,
    unsigned short* __restrict__ wqkv, unsigned short* __restrict__ wp,
    float* __restrict__ bias_qkv) {
  const int blk = blockIdx.x;
  if (blk < 8192) {                          // x: 8.4M floats, float4 per thread
    const size_t i = (size_t)blk * 256 + threadIdx.x;
    const float4 v = ((const float4*)x)[i];
    ushort4 o;
    o.x = f2b(v.x); o.y = f2b(v.y); o.z = f2b(v.z); o.w = f2b(v.w);
    ((ushort4*)xb)[i] = o;
    return;
  }
  const int idx = (blk - 8192) * 256 + threadIdx.x;
  if (idx < 786432) {                       // 1536*512
    const int m = idx >> 9, i = idx & 511;
    const float* W = (m < 512) ? Wq : ((m < 1024) ? Wk : Wv);
    wqkv[idx] = f2b(W[(m & 511) * 512 + i]);
    return;
  }
  const int j = idx - 786432;
  if (j < 262144) { wp[j] = f2b(Wp[j]); return; }
  const int c = j - 262144;
  if (c < 1536)
    bias_qkv[c] = (c < 512) ? bq[c] : ((c < 1024) ? bk[c - 512] : bv[c - 1024]);
}

// ---------------- bf16 GEMM, B^T input, XCD-swizzled, BK=64 + XOR LDS swizzle ----------------
// SOFT=1: fused per-head softmax on q/k regions, coalesced bf16 store via padded LDS repack.
// SOFT=0: fp32 store + bias, coalesced float4 via padded LDS repack.
template<int SOFT>
__global__ __launch_bounds__(256, 2) void gemm_bt(
    const unsigned short* __restrict__ A,
    const unsigned short* __restrict__ Bm,
    const float* __restrict__ bias,
    void* __restrict__ C,
    int M, int N, int K, int ldc)
{
  // staging needs 16384 shorts; bf16 repack needs 64*132=8448; fp32 repack needs
  // 64*130 floats = 16640 shorts. 16640 shorts = 33280 B -> still 4 blocks/CU by LDS.
  __shared__ unsigned short sh[16640];
  unsigned short* As = sh;
  unsigned short* Bs = sh + 128 * 64;
  const int tid  = threadIdx.x;
  const int wave = tid >> 6;
  const int lane = tid & 63;
  const int quad = lane >> 4;
  const int lr   = lane & 15;
  const int sw7  = lr & 7;
  // XCD swizzle: keep all n-tiles of an m-tile on one XCD (L2 A-reuse)
  const int bid  = ((blockIdx.x & 7) * (gridDim.x >> 3)) + (blockIdx.x >> 3);
  const int nt   = N >> 7;
  const int bn   = (bid % nt) << 7;
  const int bm   = (bid / nt) << 7;
  const int half = wave >> 1;
  const int wm   = half << 6;
  const int wn   = (wave & 1) << 6;

  floatx4 acc[4][4] = {};

  // staging: thread t -> row = t/8 (+32/round), global 16B chunk = (t&7) ^ (row&7)
  // gl_lds16 writes lane l -> ldsbase + 16*l, so LDS chunk (t&7) of row holds
  // global chunk (t&7)^(row&7): XOR swizzle kills the 128B-row bank alias.
  const int srow = tid >> 3;
  const int scol = ((tid & 7) ^ ((tid >> 3) & 7)) << 3;
  const unsigned short* Ag = A + (size_t)(bm + srow) * K + scol;
  const unsigned short* Bg = Bm + (size_t)(bn + srow) * K + scol;
  unsigned short* Al = As + (wave << 9);   // wave*512 shorts = 1 KB
  unsigned short* Bl = Bs + (wave << 9);

  for (int k0 = 0; k0 < K; k0 += 64) {
    __syncthreads();
    gl_lds16(Ag + k0,                    Al);
    gl_lds16(Ag + (size_t)32 * K + k0,   Al + 2048);
    gl_lds16(Ag + (size_t)64 * K + k0,   Al + 4096);
    gl_lds16(Ag + (size_t)96 * K + k0,   Al + 6144);
    gl_lds16(Bg + k0,                    Bl);
    gl_lds16(Bg + (size_t)32 * K + k0,   Bl + 2048);
    gl_lds16(Bg + (size_t)64 * K + k0,   Bl + 4096);
    gl_lds16(Bg + (size_t)96 * K + k0,   Bl + 6144);
    __syncthreads();

#pragma unroll
    for (int kk = 0; kk < 2; kk++) {
      const int coff = ((((kk << 2) + quad) ^ sw7) << 3);
      frag8 af[4], bf[4];
#pragma unroll
      for (int i = 0; i < 4; i++)
        af[i] = *(const frag8*)&As[(wm + (i << 4) + lr) * 64 + coff];
#pragma unroll
      for (int j = 0; j < 4; j++)
        bf[j] = *(const frag8*)&Bs[(wn + (j << 4) + lr) * 64 + coff];
#pragma unroll
      for (int i = 0; i < 4; i++)
#pragma unroll
        for (int j = 0; j < 4; j++)
          acc[i][j] = __builtin_amdgcn_mfma_f32_16x16x32_bf16(af[i], bf[j], acc[i][j], 0, 0, 0);
    }
  }

  // epilogue: C/D layout col=lane&15, row=quad*4+reg
  const int ccol0 = bn + wn + lr;

#pragma unroll
  for (int j = 0; j < 4; j++) {
    const float bv = bias[ccol0 + (j << 4)];
#pragma unroll
    for (int i = 0; i < 4; i++)
#pragma unroll
      for (int r = 0; r < 4; r++)
        acc[i][j][r] += bv;
  }

  if (SOFT) {
    const int region = (bn + wn) >> 9;   // 0=q, 1=k, 2=v (wave-uniform)
    if (region < 2) {
#pragma unroll
      for (int i = 0; i < 4; i++)
#pragma unroll
        for (int r = 0; r < 4; r++) {
          float e0 = __expf(acc[i][0][r]);
          float e1 = __expf(acc[i][1][r]);
          float e2 = __expf(acc[i][2][r]);
          float e3 = __expf(acc[i][3][r]);
          float s = e0 + e1 + e2 + e3;
          s += __shfl_xor(s, 1);
          s += __shfl_xor(s, 2);
          s += __shfl_xor(s, 4);
          s += __shfl_xor(s, 8);
          const float inv = 1.f / s;
          acc[i][0][r] = e0 * inv; acc[i][1][r] = e1 * inv;
          acc[i][2][r] = e2 * inv; acc[i][3][r] = e3 * inv;
        }
    }
    // coalesced bf16 store via padded LDS repack (stride 132: quads 8 banks apart, 2-way max)
    unsigned short* os = sh;
#pragma unroll
    for (int p = 0; p < 2; p++) {
      __syncthreads();
      if (half == p) {
#pragma unroll
        for (int i = 0; i < 4; i++)
#pragma unroll
          for (int j = 0; j < 4; j++)
#pragma unroll
            for (int r = 0; r < 4; r++)
              os[((i << 4) + (quad << 2) + r) * 132 + wn + (j << 4) + lr] = f2b(acc[i][j][r]);
      }
      __syncthreads();
#pragma unroll
      for (int it = 0; it < 4; it++) {
        const int idx = (it << 8) + tid;   // 1024 uint4 total
        const int row = idx >> 4;
        const int c8  = (idx & 15) << 3;
        *(uint4*)((unsigned short*)C + (size_t)(bm + (p << 6) + row) * ldc + bn + c8) =
            *(const uint4*)&os[row * 132 + c8];
      }
    }
  } else {
    // coalesced fp32 store via padded LDS repack (stride 130 floats: conflict-free)
    float* osf = (float*)sh;
#pragma unroll
    for (int p = 0; p < 2; p++) {
      __syncthreads();
      if (half == p) {
#pragma unroll
        for (int i = 0; i < 4; i++)
#pragma unroll
          for (int j = 0; j < 4; j++)
#pragma unroll
            for (int r = 0; r < 4; r++)
              osf[((i << 4) + (quad << 2) + r) * 130 + wn + (j << 4) + lr] = acc[i][j][r];
      }
      __syncthreads();
#pragma unroll
      for (int it = 0; it < 8; it++) {
        const int idx = (it << 8) + tid;   // 2048 float4 total
        const int row = idx >> 5;
        const int c4  = (idx & 31) << 2;
        *(float4*)((float*)C + (size_t)(bm + (p << 6) + row) * ldc + bn + c4) =
            *(const float4*)&osf[row * 130 + c4];
      }
    }
  }
}

// ---------------- partial ctxT[e][d] + ksum partial per (chunk,bh) ----------------
__global__ __launch_bounds__(256) void kv_context(const unsigned short* __restrict__ qkv,
                                                  float* __restrict__ part,
                                                  float* __restrict__ ksp) {
  const int bid = blockIdx.x;          // bh(32) x tc(32), tc-fast
  const int tc  = bid & 31;
  const int bh  = bid >> 5;
  const int b   = bh >> 3, h = bh & 7;
  __shared__ float ks[16 * 64];
  __shared__ float vs[16 * 64];
  const int tid = threadIdx.x;
  const int ty = tid >> 4, tx = tid & 15;
  floatx4 acc[4] = {};
  floatx4 ksacc = {0.f, 0.f, 0.f, 0.f};

  const int si    = tid << 3;
  const int strow = si >> 7;
  const int sw    = si & 127;
  const int t0    = b * TT + tc * 128;
  const unsigned short* gcol = qkv + ((sw < 64) ? (512 + h * 64 + sw)
                                                : (1024 + h * 64 + (sw - 64)));
  float* sdst = (sw < 64) ? &ks[strow * 64 + sw] : &vs[strow * 64 + (sw - 64)];

  for (int tt = 0; tt < 128; tt += 16) {
    __syncthreads();
    const uint4 raw = *(const uint4*)(gcol + (size_t)(t0 + tt + strow) * NQKV);
    const floatx4 f0 = {blo(raw.x), bhi(raw.x), blo(raw.y), bhi(raw.y)};
    const floatx4 f1 = {blo(raw.z), bhi(raw.z), blo(raw.w), bhi(raw.w)};
    *(floatx4*)sdst = f0;
    *(floatx4*)(sdst + 4) = f1;
    __syncthreads();
#pragma unroll
    for (int t = 0; t < 16; t++) {
      const floatx4 vb = *(const floatx4*)&vs[t * 64 + (ty << 2)];  // 4 e's
      const floatx4 kb = *(const floatx4*)&ks[t * 64 + (tx << 2)];  // 4 d's
      acc[0] += vb.x * kb;
      acc[1] += vb.y * kb;
      acc[2] += vb.z * kb;
      acc[3] += vb.w * kb;
    }
    ksacc += *(const floatx4*)&ks[ty * 64 + (tx << 2)];  // token t==ty slice
  }
  // reduce ksacc across ty via LDS (vs is dead)
  __syncthreads();
  *(floatx4*)&vs[ty * 64 + (tx << 2)] = ksacc;
  __syncthreads();

  float* pg = part + ((size_t)(tc * 32 + bh) << 12) + (size_t)(ty << 2) * 64 + (tx << 2);
#pragma unroll
  for (int i = 0; i < 4; i++)
    *(floatx4*)(pg + i * 64) = acc[i];

  if (tid < 64) {
    float s = 0.f;
    for (int t2 = 0; t2 < 16; t2++) s += vs[t2 * 64 + tid];
    ksp[(tc * 32 + bh) * 64 + tid] = s;
  }
}

// ---------------- reduce partials -> ctxb bf16 [bh][80][64] ----------------
// rows 0-63 = ctxT, row 64 = ksum, rows 65-79 = 0
__global__ __launch_bounds__(256) void ctx_reduce(const float* __restrict__ part,
                                                  const float* __restrict__ ksp,
                                                  unsigned short* __restrict__ ctxb) {
  const int bh = blockIdx.x / 5, g = blockIdx.x % 5;
  const int row = (g << 4) + (threadIdx.x >> 4);
  const int d0  = (threadIdx.x & 15) << 2;
  floatx4 s = {0.f, 0.f, 0.f, 0.f};
  if (row < 64) {
    const float* p = part + ((size_t)bh << 12) + row * 64 + d0;
    for (int c = 0; c < 32; c++)
      s += *(const floatx4*)(p + ((size_t)c << 17));
  } else if (row == 64) {
    const float* p = ksp + bh * 64 + d0;
    for (int c = 0; c < 32; c++)
      s += *(const floatx4*)(p + (c << 11));
  }
  ushort4 o;
  o.x = f2b(s.x); o.y = f2b(s.y); o.z = f2b(s.z); o.w = f2b(s.w);
  *(ushort4*)&ctxb[(size_t)bh * 5120 + (row << 6) + d0] = o;
}

// ---------------- attn_out via MFMA: outT[e][t] = ctxT[e][:]·q'[t][:] ----------------
__global__ __launch_bounds__(256) void attn_out(const unsigned short* __restrict__ qkv,
                                                const unsigned short* __restrict__ ctxb,
                                                unsigned short* __restrict__ opre) {
  const int tc = blockIdx.x >> 5;      // bh-fast
  const int bh = blockIdx.x & 31;
  const int b = bh >> 3, h = bh & 7;
  const int t0 = b * TT + (tc << 6);
  __shared__ unsigned short sh[144 * 72];   // qs[64][72] | cs[80][72] (cs reused as os)
  unsigned short* qs = sh;
  unsigned short* cs = sh + 64 * 72;
  unsigned short* os = cs;
  const int tid = threadIdx.x;

  for (int i = tid; i < 512; i += 256) {
    const int row = i >> 3, c8 = (i & 7) << 3;
    *(uint4*)&qs[row * 72 + c8] =
        *(const uint4*)&qkv[(size_t)(t0 + row) * NQKV + h * 64 + c8];
  }
  for (int i = tid; i < 640; i += 256) {
    const int row = i >> 3, c8 = (i & 7) << 3;
    *(uint4*)&cs[row * 72 + c8] =
        *(const uint4*)&ctxb[(size_t)bh * 5120 + (row << 6) + c8];
  }
  __syncthreads();

  const int lane = tid & 63, w = tid >> 6, quad = lane >> 4, lr = lane & 15;
  floatx4 acc[5] = {};
#pragma unroll
  for (int k2 = 0; k2 < 2; k2++) {
    const int d0 = (k2 << 5) + (quad << 3);
    const frag8 bf = *(const frag8*)&qs[((w << 4) + lr) * 72 + d0];
#pragma unroll
    for (int et = 0; et < 5; et++) {
      const frag8 af = *(const frag8*)&cs[(et * 16 + lr) * 72 + d0];
      acc[et] = __builtin_amdgcn_mfma_f32_16x16x32_bf16(af, bf, acc[et], 0, 0, 0);
    }
  }
  const float dinv = 1.f / __shfl(acc[4][0], lr);
  __syncthreads();                      // done reading cs; reuse as os

  const int trow = (w << 4) + lr;
#pragma unroll
  for (int et = 0; et < 4; et++)
#pragma unroll
    for (int r = 0; r < 4; r++) {
      const int e = et * 16 + (quad << 2) + r;
      const float qv = b2f(qs[trow * 72 + e]);
      os[trow * 72 + e] = f2b(acc[et][r] * dinv + qv);
    }
  __syncthreads();

  for (int i = tid; i < 512; i += 256) {
    const int row = i >> 3, c8 = (i & 7) << 3;
    *(uint4*)&opre[(size_t)(t0 + row) * KDIM + h * 64 + c8] = *(const uint4*)&os[row * 72 + c8];
  }
}

// ---------------- launch ----------------
extern "C" void kernel_launch(void* const* d_in, const int* in_sizes, int n_in,
                              void* d_out, int out_size, void* d_ws, size_t ws_size,
                              hipStream_t stream) {
  (void)in_sizes; (void)n_in; (void)out_size; (void)ws_size;
  const float* x  = (const float*)d_in[0];
  const float* Wq = (const float*)d_in[1];
  const float* bq = (const float*)d_in[2];
  const float* Wk = (const float*)d_in[3];
  const float* bk = (const float*)d_in[4];
  const float* Wv = (const float*)d_in[5];
  const float* bv = (const float*)d_in[6];
  const float* Wp = (const float*)d_in[7];
  const float* bp = (const float*)d_in[8];

  char* w = (char*)d_ws;
  unsigned short* xb   = (unsigned short*)w; w += (size_t)NTOK * KDIM * 2;   // 16 MB
  float* part          = (float*)xb;         // alias: xb dead after qkv GEMM
  unsigned short* wqkv = (unsigned short*)w; w += (size_t)NQKV * KDIM * 2;   // 1.5 MB
  unsigned short* wp   = (unsigned short*)w; w += (size_t)KDIM * KDIM * 2;   // 0.5 MB
  float* bias_qkv      = (float*)w;          w += (size_t)NQKV * 4;          // 6 KB
  float* ksp           = (float*)w;          w += (size_t)1024 * 64 * 4;     // 256 KB
  unsigned short* ctxb = (unsigned short*)w; w += (size_t)32 * 80 * 64 * 2;  // 320 KB
  unsigned short* qkv  = (unsigned short*)w; w += (size_t)NTOK * NQKV * 2;   // 48 MB
  unsigned short* opre = (unsigned short*)w; w += (size_t)NTOK * KDIM * 2;   // 16 MB

  cvt_all<<<12294, 256, 0, stream>>>(x, Wq, Wk, Wv, Wp, bq, bk, bv,
                                     xb, wqkv, wp, bias_qkv);
  gemm_bt<1><<<(NTOK / 128) * (NQKV / 128), 256, 0, stream>>>(
      xb, wqkv, bias_qkv, qkv, NTOK, NQKV, KDIM, NQKV);
  kv_context<<<1024, 256, 0, stream>>>(qkv, part, ksp);
  ctx_reduce<<<160, 256, 0, stream>>>(part, ksp, ctxb);
  attn_out<<<2048, 256, 0, stream>>>(qkv, ctxb, opre);
  gemm_bt<0><<<(NTOK / 128) * (KDIM / 128), 256, 0, stream>>>(
      opre, wp, bp, d_out, NTOK, KDIM, KDIM, KDIM);
}